// Round 7
// baseline (8795.911 us; speedup 1.0000x reference)
//
#include <hip/hip_runtime.h>
#include <stdint.h>

#define T_STEPS 512
#define NB 64
#define NI 512
#define NH 1024
#define NBLK 128
#define DEPTH 32
// gate-cols total = 4*NH = 4096

typedef __attribute__((ext_vector_type(8))) short short8;
typedef __attribute__((ext_vector_type(4))) float floatx4;
typedef __attribute__((ext_vector_type(16))) float floatx16;
typedef __attribute__((ext_vector_type(4))) unsigned short ushortx4;

__device__ __forceinline__ unsigned short f2bf(float f) {
  union { float f; uint32_t u; } v; v.f = f;
  return (unsigned short)((v.u + 0x7FFFu + ((v.u >> 16) & 1u)) >> 16);
}
__device__ __forceinline__ float bf2f(unsigned short s) {
  union { uint32_t u; float f; } v; v.u = ((uint32_t)s) << 16; return v.f;
}
__device__ __forceinline__ float sigmoid_f(float x) {
  return 1.0f / (1.0f + __expf(-x));
}
__device__ __forceinline__ float tanh_f(float x) {
  float xx = fminf(fmaxf(x, -15.0f), 15.0f);
  float e = __expf(2.0f * xx);
  return (e - 1.0f) / (e + 1.0f);
}

// ---------------- prep kernels ----------------

__global__ void convert_x(const float* __restrict__ X, unsigned short* __restrict__ Xb) {
  int i = blockIdx.x * 256 + threadIdx.x;
  floatx4 x = ((const floatx4*)X)[i];
  ushortx4 o;
  o[0] = f2bf(x[0]); o[1] = f2bf(x[1]); o[2] = f2bf(x[2]); o[3] = f2bf(x[3]);
  ((ushortx4*)Xb)[i] = o;
}

// in [G][K][N] fp32 -> out [G][N][K] bf16 (n-major so K is contiguous)
__global__ void transpose_bf16(const float* __restrict__ in, unsigned short* __restrict__ outp,
                               int K, int N) {
  __shared__ float tile[64][65];
  int g = blockIdx.z;
  int k0 = blockIdx.x * 64, n0 = blockIdx.y * 64;
  int tx = threadIdx.x & 63, ty = threadIdx.x >> 6;
  const float* src = in + (size_t)g * K * N;
  unsigned short* dst = outp + (size_t)g * K * N;
#pragma unroll
  for (int i = 0; i < 16; i++) {
    int r = ty * 16 + i;
    tile[r][tx] = src[(size_t)(k0 + r) * N + n0 + tx];
  }
  __syncthreads();
#pragma unroll
  for (int i = 0; i < 16; i++) {
    int r = ty * 16 + i;
    dst[(size_t)(n0 + r) * K + k0 + tx] = f2bf(tile[tx][r]);
  }
}

// bias = bi + bh; hbuf: buf0 = bf16(h0), buf1/buf2 = sentinel 0xFFFF
__global__ void prep_small(const float* __restrict__ bi, const float* __restrict__ bh,
                           const float* __restrict__ h0, float* __restrict__ bias,
                           unsigned short* __restrict__ hbuf) {
  int i = blockIdx.x * 256 + threadIdx.x;
  if (i < 4 * NH) bias[i] = bi[i] + bh[i];
  if (i < NB * NH) hbuf[i] = f2bf(h0[i]);
  if (i < NB * NH) ((unsigned*)hbuf)[NB * NH / 2 + i] = 0xFFFFFFFFu;  // buf1+buf2
}

// ---------------- Zx GEMM -> block-major Zq layout (R5 geometry) ----------------
// Zq element index: ((((t*4 + g)*128 + bk)*2 + wm)*2 + half)*8 + jj)*16 + rr
// where b = wm*32 + row32, row32 = (rr&3) | (half<<2) | ((rr>>2)<<3), j = bk*8 + jj.
__global__ __launch_bounds__(256) void gemm_zx(
    const unsigned short* __restrict__ Xb,
    const unsigned short* __restrict__ WibT,
    const float* __restrict__ bias,
    unsigned short* __restrict__ Zq) {
  __shared__ __align__(16) unsigned short As[128][40];  // +8 pad
  __shared__ __align__(16) unsigned short Bs[128][40];
  __shared__ __align__(16) unsigned short stg[16384];   // 32 KB stage
  const int g = blockIdx.z;
  const int m0 = blockIdx.x * 128;
  const int n0 = blockIdx.y * 128;
  const int tid = threadIdx.x;
  const int lane = tid & 63;
  const int wave = tid >> 6;
  const int wm = wave & 1, wn = wave >> 1;
  const int fr = lane & 15;
  const int fq = (lane >> 4) * 8;

  const unsigned short* Bsrc = WibT + (size_t)g * NH * NI;

  floatx4 acc[4][4];
#pragma unroll
  for (int a = 0; a < 4; a++)
#pragma unroll
    for (int b = 0; b < 4; b++)
#pragma unroll
      for (int z = 0; z < 4; z++) acc[a][b][z] = 0.0f;

  for (int k0 = 0; k0 < NI; k0 += 32) {
#pragma unroll
    for (int it = 0; it < 2; it++) {
      int c = tid + it * 256;
      int row = c >> 2, kc = (c & 3) * 8;
      *(uint4*)(&As[row][kc]) = *(const uint4*)(Xb + (size_t)(m0 + row) * NI + k0 + kc);
      *(uint4*)(&Bs[row][kc]) = *(const uint4*)(Bsrc + (size_t)(n0 + row) * NI + k0 + kc);
    }
    __syncthreads();
    short8 af[4], bf[4];
#pragma unroll
    for (int ms = 0; ms < 4; ms++) af[ms] = *(const short8*)(&As[wm * 64 + ms * 16 + fr][fq]);
#pragma unroll
    for (int ns = 0; ns < 4; ns++) bf[ns] = *(const short8*)(&Bs[wn * 64 + ns * 16 + fr][fq]);
#pragma unroll
    for (int ms = 0; ms < 4; ms++)
#pragma unroll
      for (int ns = 0; ns < 4; ns++)
        acc[ms][ns] = __builtin_amdgcn_mfma_f32_16x16x32_bf16(af[ms], bf[ns], acc[ms][ns], 0, 0, 0);
    __syncthreads();
  }

#pragma unroll
  for (int ns = 0; ns < 4; ns++) {
    int jrel = wn * 64 + ns * 16 + fr;        // col - n0, 0..127
    float bs = bias[g * NH + n0 + jrel];
    int bkp = jrel >> 3, jj = jrel & 7;
#pragma unroll
    for (int ms = 0; ms < 4; ms++) {
#pragma unroll
      for (int r = 0; r < 4; r++) {
        int mrel = wm * 64 + ms * 16 + (lane >> 4) * 4 + r;   // 0..127
        int tp = mrel >> 6, b = mrel & 63;
        int wm2 = b >> 5, row32 = b & 31;
        int half2 = (row32 >> 2) & 1;
        int rr = (row32 & 3) | ((row32 >> 3) << 2);
        int idx = (((((tp * 16 + bkp) * 2 + wm2) * 2 + half2) * 8 + jj) * 16) + rr;
        stg[idx] = f2bf(acc[ms][ns][r] + bs);
      }
    }
  }
  __syncthreads();
  const size_t t0 = (size_t)(m0 >> 6);
  const int bk0 = n0 >> 3;
#pragma unroll
  for (int tp = 0; tp < 2; tp++) {
    size_t gbase = (((t0 + tp) * 4 + g) * 128 + bk0) * 512;   // elements
#pragma unroll
    for (int c = 0; c < 4; c++) {
      int e = c * 2048 + tid * 8;
      *(uint4*)(Zq + gbase + e) = *(const uint4*)(stg + tp * 8192 + e);
    }
  }
}

// ---------------- persistent recurrent kernel ----------------
// R10 = R9 (flag-free dataflow) with the validation bug fixed:
//  * R9 HANG ROOT CAUSE: chunk_stale reduced 8 dwords, but a chunk is
//    global_load_dwordx4 = 16 B = 4 dwords (short8). u[4..7] were UNDEFINED
//    register garbage -> any 0xFFFF half -> infinite retry -> hang. Fixed:
//    3x v_pk_max_u16 over exactly 4 dwords, union sized 16 B both members.
//  Design (unchanged from R9):
//  * hbuf[3] triple buffer; buffer to be written at t+1 is sentinel-filled
//    (0xFFFF = bf16 NaN; h = sig*tanh in (-1,1) can never produce it).
//  * Consumers load h chunks (bypass sc0 sc1, counted-vmcnt window) and VALIDATE
//    IN REGISTERS; stale -> wave-uniform reload-retry (FIFO keeps counted waits
//    correct; retry drains vmcnt, later waits become no-ops, later chunks simply
//    validate/retry on their own).
//  * Producer epilogue: issue sentinel-clears of buf[(t+2)%3] (own 8 cols) ->
//    gate VALU (hides clear flight) -> vmcnt(0) (clears only) -> publish h ->
//    out/Zq. NO release drain, NO flag, NO arrive spin, NO __syncthreads.
//  Safety: A reaching step t+1's clear of buf[t%3] requires A validated ALL of
//  h_{t+1} => every block published h_{t+1} => every block finished reading h_t
//  (incl. retries) => clear cannot race readers. Clears drained BEFORE h publish
//  => validated-h_{t-1} consumers never read pre-clear garbage as h_t. 2 B
//  stores atomic => partial visibility just retries. Waits only on previous-step
//  data => deadlock-free (grounds out at t=0).

__device__ __forceinline__ bool chunk_stale(const short8& a) {
  union { short8 s; unsigned u[4]; } x; x.s = a;   // 16 B both members
  unsigned m0, m1;
  asm("v_pk_max_u16 %0, %1, %2" : "=v"(m0) : "v"(x.u[0]), "v"(x.u[1]));
  asm("v_pk_max_u16 %0, %1, %2" : "=v"(m1) : "v"(x.u[2]), "v"(x.u[3]));
  asm("v_pk_max_u16 %0, %0, %1" : "+v"(m0) : "v"(m1));
  return ((m0 & 0xFFFFu) == 0xFFFFu) || ((m0 >> 16) == 0xFFFFu);
}

template<int C>
__device__ __forceinline__ void load_a_c(const unsigned short* ap, short8 (&areg)[64]) {
  asm volatile("global_load_dwordx4 %0, %1, off offset:%2 sc0 sc1"
               : "=v"(areg[C]) : "v"(ap), "i"(C * 32));
}

template<int C>
__device__ __forceinline__ void load_b_c(const unsigned short* bfr, int lane, short8 (&bs)[64]) {
  bs[C] = *(const short8*)(&bfr[((size_t)(C * 64) + lane) * 8]);
}

template<int S, int I>
struct PrologR {
  static __device__ __forceinline__ void run(const unsigned short* ap, short8 (&areg)[64]) {
    load_a_c<(S + I) & 63>(ap, areg);
    PrologR<S, I + 1>::run(ap, areg);
  }
};
template<int S>
struct PrologR<S, DEPTH> {
  static __device__ __forceinline__ void run(const unsigned short*, short8 (&)[64]) {}
};

template<int S, int I>
struct ChunksR {
  static __device__ __forceinline__ void run(const unsigned short* ap, const unsigned short* bfr,
                                             int lane, short8 (&areg)[64], short8 (&bs)[64],
                                             floatx16& acc0, floatx16& acc1) {
    if constexpr (I + DEPTH < 64) load_a_c<(S + I + DEPTH) & 63>(ap, areg);
    if constexpr (I + 4 < 64) load_b_c<(S + I + 4) & 63>(bfr, lane, bs);
    constexpr int NOUT = (I + DEPTH < 64) ? DEPTH : (63 - I);
    constexpr int C = (S + I) & 63;
    asm volatile("s_waitcnt vmcnt(%1)" : "+v"(areg[C]) : "i"(NOUT) : "memory");
    // sentinel validation; retry (reload+drain) only while producer data missing
    bool st = chunk_stale(areg[C]);
    while (__any((int)st)) {
      asm volatile("global_load_dwordx4 %0, %1, off offset:%2 sc0 sc1"
                   : "=v"(areg[C]) : "v"(ap), "i"(C * 32));
      asm volatile("s_waitcnt vmcnt(0)" : "+v"(areg[C]) :: "memory");
      st = chunk_stale(areg[C]);
    }
    if constexpr ((I & 1) == 0)
      acc0 = __builtin_amdgcn_mfma_f32_32x32x16_bf16(areg[C], bs[C], acc0, 0, 0, 0);
    else
      acc1 = __builtin_amdgcn_mfma_f32_32x32x16_bf16(areg[C], bs[C], acc1, 0, 0, 0);
    ChunksR<S, I + 1>::run(ap, bfr, lane, areg, bs, acc0, acc1);
  }
};
template<int S>
struct ChunksR<S, 64> {
  static __device__ __forceinline__ void run(const unsigned short*, const unsigned short*,
                                             int, short8 (&)[64], short8 (&)[64],
                                             floatx16&, floatx16&) {}
};

template<int S>
__device__ __forceinline__ void lstm_step(
    int t, const unsigned short* __restrict__ Zq, unsigned short* __restrict__ hbuf,
    float* __restrict__ out, const unsigned short* bfr,
    int tid, int lane, int wm, int nl, int g0, int jj, int half, int bk, int j0,
    size_t zoff, const int (&brow)[16], float (&creg)[16],
    uint4 (&zc)[2], uint4 (&zn)[2]) {
  const int hsz = NB * NH;

  // clean vmcnt domain for the counted window (drains prior h/out/Zq ops)
  asm volatile("s_waitcnt vmcnt(0)" ::: "memory");
  __builtin_amdgcn_sched_barrier(0);

  const unsigned short* hin = hbuf + (size_t)(t % 3) * hsz;
  unsigned short* hout = hbuf + (size_t)((t + 1) % 3) * hsz;
  unsigned* hclr = (unsigned*)(hbuf + (size_t)((t + 2) % 3) * hsz);
  const unsigned short* ap = hin + (size_t)(wm * 32 + nl) * NH + half * 8;

  floatx16 acc0, acc1;
#pragma unroll
  for (int z = 0; z < 16; z++) { acc0[z] = 0.0f; acc1[z] = 0.0f; }

  short8 areg[64];
  short8 bs[64];
  PrologR<S, 0>::run(ap, areg);
  load_b_c<(S + 0) & 63>(bfr, lane, bs);
  load_b_c<(S + 1) & 63>(bfr, lane, bs);
  load_b_c<(S + 2) & 63>(bfr, lane, bs);
  load_b_c<(S + 3) & 63>(bfr, lane, bs);
  ChunksR<S, 0>::run(ap, bfr, lane, areg, bs, acc0, acc1);
  __builtin_amdgcn_sched_barrier(0);

  // ---- epilogue ----
  // 1) issue sentinel-clears of buf[(t+2)%3] (the buffer I write at t+1);
  //    its readers are provably done (I validated all of h_t above).
  if (t + 1 < T_STEPS) {
#pragma unroll
    for (int u = 0; u < 2; u++) {
      int e = tid * 2 + u;               // 0..255: 64 rows x 4 dwords (8 cols)
      int r = e >> 2, d = e & 3;
      __hip_atomic_store(hclr + (size_t)r * (NH / 2) + (j0 >> 1) + d, 0xFFFFFFFFu,
                         __ATOMIC_RELAXED, __HIP_MEMORY_SCOPE_AGENT);
    }
  }

#pragma unroll
  for (int z = 0; z < 16; z++) acc0[z] += acc1[z];

  unsigned zd[8];
  zd[0] = zc[0].x; zd[1] = zc[0].y; zd[2] = zc[0].z; zd[3] = zc[0].w;
  zd[4] = zc[1].x; zd[5] = zc[1].y; zd[6] = zc[1].z; zd[7] = zc[1].w;

  // 2) gate VALU (hides clear-store flight)
  float harr[16];
  unsigned short hus[16];
#pragma unroll
  for (int r = 0; r < 16; r++) {
    unsigned dw = zd[r >> 1];
    float zxv = bf2f((unsigned short)((r & 1) ? (dw >> 16) : (dw & 0xffffu)));
    float z0 = acc0[r] + zxv;            // gate g0
    float z1 = __shfl_xor(z0, 8);        // gate g0^1
    float z2 = __shfl_xor(z0, 16);       // gate g0^2
    float z3 = __shfl_xor(z1, 16);       // gate g0^3
    bool bb0 = (g0 & 1) != 0, bb1 = (g0 & 2) != 0;
    float zf = bb1 ? (bb0 ? z3 : z2) : (bb0 ? z1 : z0);
    float zi = bb1 ? (bb0 ? z2 : z3) : (bb0 ? z0 : z1);
    float zg = bb1 ? (bb0 ? z1 : z0) : (bb0 ? z3 : z2);
    float zo = bb1 ? (bb0 ? z0 : z1) : (bb0 ? z2 : z3);
    float fg = sigmoid_f(zf);
    float ig = sigmoid_f(zi);
    float gg = tanh_f(zg);
    float og = sigmoid_f(zo);
    float c = fg * creg[r] + ig * gg;
    creg[r] = c;
    float h = og * tanh_f(c);
    harr[r] = h;
    hus[r] = f2bf(h);
  }

  // 3) drain the clears (only clears outstanding here), then publish h
  asm volatile("s_waitcnt vmcnt(0)" ::: "memory");
  if (t + 1 < T_STEPS && g0 == 0) {
#pragma unroll
    for (int r = 0; r < 16; r++)
      __hip_atomic_store(&hout[(size_t)brow[r] * NH + j0 + jj], hus[r],
                         __ATOMIC_RELAXED, __HIP_MEMORY_SCOPE_AGENT);
  }

  // 4) out stores (nt, off the dataflow path; drained at next step top)
  if (g0 == 0) {
#pragma unroll
    for (int r = 0; r < 16; r++) {
      size_t oidx = (size_t)brow[r] * NH + j0 + jj;
      __builtin_nontemporal_store(harr[r], &out[(size_t)t * hsz + oidx]);
      if (t == T_STEPS - 1)
        __builtin_nontemporal_store(harr[r], &out[(size_t)T_STEPS * hsz + oidx]);  // h_n
    }
  }

  // 5) Zq prefetch for t+1
  if (t + 1 < T_STEPS) {
    const unsigned short* zp = Zq + (size_t)(t + 1) * 262144 + zoff;
    asm volatile("global_load_dwordx4 %0, %1, off nt" : "=v"(zn[0]) : "v"(zp));
    asm volatile("global_load_dwordx4 %0, %1, off offset:16 nt" : "=v"(zn[1]) : "v"(zp));
  }
}

template<int S>
__device__ __forceinline__ void lstm_loop(
    const unsigned short* __restrict__ Zq, unsigned short* __restrict__ hbuf,
    float* __restrict__ out, const unsigned short* bfr,
    int tid, int lane, int wm, int nl, int g0, int jj, int half, int bk, int j0,
    size_t zoff, const int (&brow)[16], float (&creg)[16]) {
  uint4 zA[2], zB[2];
  {
    const unsigned short* zp = Zq + zoff;
    asm volatile("global_load_dwordx4 %0, %1, off nt" : "=v"(zA[0]) : "v"(zp));
    asm volatile("global_load_dwordx4 %0, %1, off offset:16 nt" : "=v"(zA[1]) : "v"(zp));
  }
  for (int t2 = 0; t2 < T_STEPS; t2 += 2) {
    lstm_step<S>(t2,     Zq, hbuf, out, bfr, tid, lane, wm, nl, g0, jj, half,
                 bk, j0, zoff, brow, creg, zA, zB);
    lstm_step<S>(t2 + 1, Zq, hbuf, out, bfr, tid, lane, wm, nl, g0, jj, half,
                 bk, j0, zoff, brow, creg, zB, zA);
  }
}

__global__ __launch_bounds__(128, 1) void lstm_persist(
    const unsigned short* __restrict__ Zq,
    const unsigned short* __restrict__ WhT,   // [4][NH(n)][NH(k)] bf16
    const float* __restrict__ c0,
    unsigned short* __restrict__ hbuf,        // 3 x NB x NH bf16 (triple buffer)
    float* __restrict__ out) {
  __shared__ __align__(16) unsigned short bfr[64 * 64 * 8];  // [kk][lane][8] = 64 KB

  const int bk = blockIdx.x;
  const int j0 = bk * 8;
  const int tid = threadIdx.x;
  const int lane = tid & 63;
  const int wm = tid >> 6;        // wave = batch half (m-tile of 32)
  const int nl = lane & 31;       // MFMA col n: gate g0 = n>>3, h-col jj = n&7
  const int g0 = nl >> 3;
  const int jj = nl & 7;
  const int half = lane >> 5;

  // Fill B fragments: B[k][n] = Wh[g][k][j0+jj] = WhT[g][j0+jj][k]
  for (int i = 0; i < 32; i++) {
    int f = tid + i * 128;        // 0..4095 = kk*64 + lane
    int fl = f & 63, kk = f >> 6;
    int n = fl & 31;
    size_t wrow = (size_t)((n >> 3) * NH + j0 + (n & 7));
    int kb = kk * 16 + (fl >> 5) * 8;
    uint4 v = *(const uint4*)(WhT + wrow * NH + kb);
    *(uint4*)(&bfr[(size_t)f * 8]) = v;
  }

  // c state in C/D layout: row = (r&3) + 8*(r>>2) + 4*half
  float creg[16];
  int brow[16];
#pragma unroll
  for (int r = 0; r < 16; r++) {
    brow[r] = wm * 32 + (r & 3) + 8 * (r >> 2) + 4 * half;
    creg[r] = c0[(size_t)brow[r] * NH + j0 + jj];
  }
  __syncthreads();

  const size_t zoff = (((((size_t)g0 * 128 + bk) * 2 + wm) * 2 + half) * 8 + jj) * 16;

  switch (bk & 3) {
    case 0: lstm_loop<0>(Zq, hbuf, out, bfr, tid, lane, wm, nl, g0, jj, half,
                         bk, j0, zoff, brow, creg); break;
    case 1: lstm_loop<16>(Zq, hbuf, out, bfr, tid, lane, wm, nl, g0, jj, half,
                          bk, j0, zoff, brow, creg); break;
    case 2: lstm_loop<32>(Zq, hbuf, out, bfr, tid, lane, wm, nl, g0, jj, half,
                          bk, j0, zoff, brow, creg); break;
    default: lstm_loop<48>(Zq, hbuf, out, bfr, tid, lane, wm, nl, g0, jj, half,
                           bk, j0, zoff, brow, creg); break;
  }

  // c_n
  if (g0 == 0) {
#pragma unroll
    for (int r = 0; r < 16; r++)
      __builtin_nontemporal_store(
          creg[r], &out[(size_t)T_STEPS * NB * NH + NB * NH + (size_t)brow[r] * NH + j0 + jj]);
  }
}

// ---------------- host launcher ----------------
extern "C" void kernel_launch(void* const* d_in, const int* in_sizes, int n_in,
                              void* d_out, int out_size, void* d_ws, size_t ws_size,
                              hipStream_t stream) {
  const float* X  = (const float*)d_in[0];
  const float* h0 = (const float*)d_in[1];
  const float* c0 = (const float*)d_in[2];
  const float* Wi = (const float*)d_in[3];
  const float* Wh = (const float*)d_in[4];
  const float* bi = (const float*)d_in[5];
  const float* bh = (const float*)d_in[6];
  float* out = (float*)d_out;

  uint8_t* ws = (uint8_t*)d_ws;
  size_t off = 0;
  auto alloc = [&](size_t bytes) -> void* {
    void* p = ws + off;
    off += (bytes + 255) & ~(size_t)255;
    return p;
  };
  unsigned short* Zq   = (unsigned short*)alloc((size_t)T_STEPS * NB * 4096 * 2);  // 268 MB
  unsigned short* Xb   = (unsigned short*)alloc((size_t)T_STEPS * NB * NI * 2);    // 33.6 MB
  unsigned short* WibT = (unsigned short*)alloc((size_t)4 * NH * NI * 2);          // 4.2 MB
  unsigned short* WhT  = (unsigned short*)alloc((size_t)4 * NH * NH * 2);          // 8.4 MB
  float* bias          = (float*)alloc((size_t)4 * NH * 4);
  unsigned short* hbuf = (unsigned short*)alloc((size_t)3 * NB * NH * 2);          // 384 KB

  if (off > ws_size) {
    hipMemsetAsync(d_out, 0x7F, (size_t)out_size * 4, stream);
    return;
  }

  convert_x<<<16384, 256, 0, stream>>>(X, Xb);
  transpose_bf16<<<dim3(8, 16, 4), 256, 0, stream>>>(Wi, WibT, NI, NH);
  transpose_bf16<<<dim3(16, 16, 4), 256, 0, stream>>>(Wh, WhT, NH, NH);
  prep_small<<<256, 256, 0, stream>>>(bi, bh, h0, bias, hbuf);
  gemm_zx<<<dim3(256, 8, 4), 256, 0, stream>>>(Xb, WibT, bias, Zq);

  lstm_persist<<<dim3(NBLK), dim3(128), 0, stream>>>(Zq, WhT, c0, hbuf, out);
}